// Round 7
// baseline (55.826 us; speedup 1.0000x reference)
//
#include <hip/hip_runtime.h>

// RBF kernel matrix: out[r,i,j] = os^2 * exp(-0.5 * ||(x1_i - x2_j)/ls||^2)
// R=4, N1=N2=4096, D=8. Output 268 MB fp32 -> write-BW bound.
// fillBuffer proves 7.1 TB/s streaming writes => floor ~38 us. We sit at 47.3
// = 38 + ~9.5 (chip VALU time) -> compute ADDS instead of hiding (convoy
// effect: store backpressure phase-locks the waves). R6: lean <=64-VGPR body
// (BJ=256 j-state in 32 regs, x1 pre-scaled into LDS) + launch_bounds(256,8)
// -> 8 waves/SIMD / 8 blocks/CU for store/compute interleave across waves.

constexpr int D     = 8;
constexpr int BROWS = 128;   // x1 rows per block (32 per wave)
constexpr int BJ    = 256;   // x2 cols per block (4 per lane)

#if __has_builtin(__builtin_amdgcn_exp2f)
#define FAST_EXP2(x) __builtin_amdgcn_exp2f(x)
#else
#define FAST_EXP2(x) __expf((x) * 0.69314718f)   // exp(x*ln2) == 2^x
#endif

__global__ __launch_bounds__(256, 8) void rbf_kernel(
    const float* __restrict__ x1, const float* __restrict__ x2,
    const float* __restrict__ ls, const float* __restrict__ osc,
    float* __restrict__ out, int N1, int N2)
{
    __shared__ float sb[D][BJ];      // x2 tile, scaled, d-major   (8 KB)
    __shared__ float sbb[BJ];        // ||b||^2 per j              (1 KB)
    __shared__ float sa[BROWS][D];   // x1 tile, scaled            (4 KB)
    __shared__ float sca[BROWS];     // -0.5*log2e*||a||^2 per row (512 B)

    const int r   = blockIdx.z;
    const int i0  = blockIdx.y * BROWS;
    const int j0  = blockIdx.x * BJ;
    const int tid = threadIdx.x;

    constexpr float L2E  = 1.44269504f;   //  log2(e)
    constexpr float NH2E = -0.72134752f;  // -0.5*log2(e)

    // inv regs live only during staging
    {
        float4 l0 = *reinterpret_cast<const float4*>(ls);
        float4 l1 = *reinterpret_cast<const float4*>(ls + 4);
        float4 inv0, inv1;
        inv0.x = 1.0f/l0.x; inv0.y = 1.0f/l0.y; inv0.z = 1.0f/l0.z; inv0.w = 1.0f/l0.w;
        inv1.x = 1.0f/l1.x; inv1.y = 1.0f/l1.y; inv1.z = 1.0f/l1.z; inv1.w = 1.0f/l1.w;

        // stage x2: one point per thread (256 pts)
        {
            const float* src = x2 + ((size_t)r * N2 + j0 + tid) * D;
            float4 v0 = *reinterpret_cast<const float4*>(src);
            float4 v1 = *reinterpret_cast<const float4*>(src + 4);
            v0.x *= inv0.x; v0.y *= inv0.y; v0.z *= inv0.z; v0.w *= inv0.w;
            v1.x *= inv1.x; v1.y *= inv1.y; v1.z *= inv1.z; v1.w *= inv1.w;
            sb[0][tid] = v0.x; sb[1][tid] = v0.y; sb[2][tid] = v0.z; sb[3][tid] = v0.w;
            sb[4][tid] = v1.x; sb[5][tid] = v1.y; sb[6][tid] = v1.z; sb[7][tid] = v1.w;
            sbb[tid] = v0.x*v0.x + v0.y*v0.y + v0.z*v0.z + v0.w*v0.w
                     + v1.x*v1.x + v1.y*v1.y + v1.z*v1.z + v1.w*v1.w;
        }
        // stage x1: threads 0..127, one row each, pre-scaled
        if (tid < BROWS) {
            const float* src = x1 + ((size_t)r * N1 + i0 + tid) * D;
            float4 v0 = *reinterpret_cast<const float4*>(src);
            float4 v1 = *reinterpret_cast<const float4*>(src + 4);
            v0.x *= inv0.x; v0.y *= inv0.y; v0.z *= inv0.z; v0.w *= inv0.w;
            v1.x *= inv1.x; v1.y *= inv1.y; v1.z *= inv1.z; v1.w *= inv1.w;
            *reinterpret_cast<float4*>(&sa[tid][0]) = v0;
            *reinterpret_cast<float4*>(&sa[tid][4]) = v1;
            sca[tid] = (v0.x*v0.x + v0.y*v0.y + v0.z*v0.z + v0.w*v0.w
                      + v1.x*v1.x + v1.y*v1.y + v1.z*v1.z + v1.w*v1.w) * NH2E;
        }
    }
    const float lg2os = __log2f(osc[0] * osc[0]);   // exact 0 for os=1
    __syncthreads();

    // ---- per-lane j-state: 32 VGPR of b + 4 of cb ----
    const int lane = tid & 63;
    const int wv   = tid >> 6;

    float4 bd[D];
#pragma unroll
    for (int d = 0; d < D; ++d)
        bd[d] = *reinterpret_cast<const float4*>(&sb[d][lane * 4]);
    float4 cb;   // -0.5*log2e*bb + log2(os^2)
    {
        const float4 bb = *reinterpret_cast<const float4*>(&sbb[lane * 4]);
        cb.x = fmaf(bb.x, NH2E, lg2os); cb.y = fmaf(bb.y, NH2E, lg2os);
        cb.z = fmaf(bb.z, NH2E, lg2os); cb.w = fmaf(bb.w, NH2E, lg2os);
    }

    float* obase = out + ((size_t)r * N1 + i0 + wv * 32) * (size_t)N2 + j0 + lane * 4;

    // ---- 32 rows per wave: {3 LDS broadcasts, 44 fma, 8 exp, 1 store} ----
#pragma unroll 4
    for (int ii = 0; ii < 32; ++ii) {
        const int row = wv * 32 + ii;
        const float4 a0 = *reinterpret_cast<const float4*>(&sa[row][0]);
        const float4 a1 = *reinterpret_cast<const float4*>(&sa[row][4]);
        const float  ca = sca[row];

        float p0 = 0.f, p1 = 0.f, p2 = 0.f, p3 = 0.f;
        const float a[D] = {a0.x, a0.y, a0.z, a0.w, a1.x, a1.y, a1.z, a1.w};
#pragma unroll
        for (int d = 0; d < D; ++d) {
            const float av = a[d];
            p0 = fmaf(av, bd[d].x, p0);
            p1 = fmaf(av, bd[d].y, p1);
            p2 = fmaf(av, bd[d].z, p2);
            p3 = fmaf(av, bd[d].w, p3);
        }
        float4 o;
        o.x = FAST_EXP2(fmaf(p0, L2E, ca + cb.x));
        o.y = FAST_EXP2(fmaf(p1, L2E, ca + cb.y));
        o.z = FAST_EXP2(fmaf(p2, L2E, ca + cb.z));
        o.w = FAST_EXP2(fmaf(p3, L2E, ca + cb.w));
        *reinterpret_cast<float4*>(obase + (size_t)ii * N2) = o;
    }
}

extern "C" void kernel_launch(void* const* d_in, const int* in_sizes, int n_in,
                              void* d_out, int out_size, void* d_ws, size_t ws_size,
                              hipStream_t stream) {
    (void)in_sizes; (void)n_in; (void)d_ws; (void)ws_size; (void)out_size;
    const float* x1  = (const float*)d_in[0];
    const float* x2  = (const float*)d_in[1];
    const float* ls  = (const float*)d_in[2];
    const float* osc = (const float*)d_in[3];
    float* out = (float*)d_out;

    const int R = 4, N1 = 4096, N2 = 4096;
    dim3 grid(N2 / BJ, N1 / BROWS, R);   // 16 x 32 x 4 = 2048 blocks
    rbf_kernel<<<grid, dim3(256), 0, stream>>>(x1, x2, ls, osc, out, N1, N2);
}

// Round 8
// 55.179 us; speedup vs baseline: 1.0117x; 1.0117x over previous
//
#include <hip/hip_runtime.h>

// RBF kernel matrix: out[r,i,j] = os^2 * exp(-0.5 * ||(x1_i - x2_j)/ls||^2)
// R=4, N1=N2=4096, D=8. Output 268 MB fp32 -> write-BW bound.
// Evidence so far: perf tracks store RUN LENGTH / stream count:
//   256B runs=55us, 1KB=51-56us, 2KB=47.4us, fill(huge runs)=38us-equiv.
// R7: wave owns 1024-j panel x 32 rows; panel's x2 in 128 VGPR (bd[4][8]);
// no LDS, no barriers; per row 4 back-to-back dwordx4 = 4KB sequential run.
// 2048 waves -> 8 streams/CU, 4x longer runs than R4.

constexpr int D     = 8;
constexpr int PANEL = 1024;  // j-span per wave
constexpr int CH    = 4;     // chunks of 256 j (64 lanes x 4)
constexpr int SEG   = 32;    // consecutive rows per wave

#if __has_builtin(__builtin_amdgcn_exp2f)
#define FAST_EXP2(x) __builtin_amdgcn_exp2f(x)
#else
#define FAST_EXP2(x) __expf((x) * 0.69314718f)   // exp(x*ln2) == 2^x
#endif

__global__ __launch_bounds__(256, 2) void rbf_kernel(
    const float* __restrict__ x1, const float* __restrict__ x2,
    const float* __restrict__ ls, const float* __restrict__ osc,
    float* __restrict__ out, int N1, int N2)
{
    const int tid  = threadIdx.x;
    const int lane = tid & 63;
    const int wid  = blockIdx.x * 4 + (tid >> 6);   // global wave id [0,2048)

    const int panel = wid >> 9;          // [0,4)
    const int r     = (wid >> 7) & 3;    // [0,4)
    const int row0  = (wid & 127) * SEG; // [0,4096)

    constexpr float L2E  = 1.44269504f;   //  log2(e)
    constexpr float NH2E = -0.72134752f;  // -0.5*log2(e)

    float4 l0 = *reinterpret_cast<const float4*>(ls);
    float4 l1 = *reinterpret_cast<const float4*>(ls + 4);
    float4 inv0, inv1;
    inv0.x = 1.0f/l0.x; inv0.y = 1.0f/l0.y; inv0.z = 1.0f/l0.z; inv0.w = 1.0f/l0.w;
    inv1.x = 1.0f/l1.x; inv1.y = 1.0f/l1.y; inv1.z = 1.0f/l1.z; inv1.w = 1.0f/l1.w;
    const float lg2os = __log2f(osc[0] * osc[0]);   // exact 0 for os=1

    // ---- prologue: lane's 16 x2 points (4 per chunk) -> registers, j-major ----
    float4 bd[CH][D];   // [chunk][dim] -> float4 over the lane's 4 j-points
    float4 cb[CH];      // -0.5*log2e*||b||^2 + lg2os, per point
#pragma unroll
    for (int c = 0; c < CH; ++c) {
        const float* bp = x2 + ((size_t)r * N2 + panel * PANEL + c * 256 + lane * 4) * D;
        float4 u[8];    // 4 points x 2 float4, scaled
#pragma unroll
        for (int p = 0; p < 4; ++p) {
            float4 v0 = *reinterpret_cast<const float4*>(bp + p * D);
            float4 v1 = *reinterpret_cast<const float4*>(bp + p * D + 4);
            v0.x *= inv0.x; v0.y *= inv0.y; v0.z *= inv0.z; v0.w *= inv0.w;
            v1.x *= inv1.x; v1.y *= inv1.y; v1.z *= inv1.z; v1.w *= inv1.w;
            u[2*p]   = v0;
            u[2*p+1] = v1;
        }
        // transpose point-major -> dim-major (all static indices -> regs)
#pragma unroll
        for (int d = 0; d < D; ++d) {
            float4 t;
            t.x = reinterpret_cast<const float*>(&u[0 + (d >> 2)])[d & 3];
            t.y = reinterpret_cast<const float*>(&u[2 + (d >> 2)])[d & 3];
            t.z = reinterpret_cast<const float*>(&u[4 + (d >> 2)])[d & 3];
            t.w = reinterpret_cast<const float*>(&u[6 + (d >> 2)])[d & 3];
            bd[c][d] = t;
        }
        float4 t;
        t.x = u[0].x*u[0].x + u[0].y*u[0].y + u[0].z*u[0].z + u[0].w*u[0].w
            + u[1].x*u[1].x + u[1].y*u[1].y + u[1].z*u[1].z + u[1].w*u[1].w;
        t.y = u[2].x*u[2].x + u[2].y*u[2].y + u[2].z*u[2].z + u[2].w*u[2].w
            + u[3].x*u[3].x + u[3].y*u[3].y + u[3].z*u[3].z + u[3].w*u[3].w;
        t.z = u[4].x*u[4].x + u[4].y*u[4].y + u[4].z*u[4].z + u[4].w*u[4].w
            + u[5].x*u[5].x + u[5].y*u[5].y + u[5].z*u[5].z + u[5].w*u[5].w;
        t.w = u[6].x*u[6].x + u[6].y*u[6].y + u[6].z*u[6].z + u[6].w*u[6].w
            + u[7].x*u[7].x + u[7].y*u[7].y + u[7].z*u[7].z + u[7].w*u[7].w;
        cb[c].x = fmaf(t.x, NH2E, lg2os);
        cb[c].y = fmaf(t.y, NH2E, lg2os);
        cb[c].z = fmaf(t.z, NH2E, lg2os);
        cb[c].w = fmaf(t.w, NH2E, lg2os);
    }

    // ---- main loop: 32 rows, each -> 4KB sequential store run ----
    const float* xrow  = x1 + ((size_t)r * N1 + row0) * D;
    float*       obase = out + ((size_t)r * N1 + row0) * (size_t)N2
                             + panel * PANEL + lane * 4;

#pragma unroll 2
    for (int s = 0; s < SEG; ++s) {
        float4 u0 = *reinterpret_cast<const float4*>(xrow + (size_t)s * D);
        float4 u1 = *reinterpret_cast<const float4*>(xrow + (size_t)s * D + 4);
        float a[D];
        a[0] = u0.x * inv0.x; a[1] = u0.y * inv0.y;
        a[2] = u0.z * inv0.z; a[3] = u0.w * inv0.w;
        a[4] = u1.x * inv1.x; a[5] = u1.y * inv1.y;
        a[6] = u1.z * inv1.z; a[7] = u1.w * inv1.w;
        float asq = 0.f;
#pragma unroll
        for (int d = 0; d < D; ++d) asq = fmaf(a[d], a[d], asq);
        const float ca = asq * NH2E;

        float* op = obase + (size_t)s * N2;
#pragma unroll
        for (int c = 0; c < CH; ++c) {
            float p0 = 0.f, p1 = 0.f, p2 = 0.f, p3 = 0.f;
#pragma unroll
            for (int d = 0; d < D; ++d) {
                const float av = a[d];
                p0 = fmaf(av, bd[c][d].x, p0);
                p1 = fmaf(av, bd[c][d].y, p1);
                p2 = fmaf(av, bd[c][d].z, p2);
                p3 = fmaf(av, bd[c][d].w, p3);
            }
            float4 o;
            o.x = FAST_EXP2(fmaf(p0, L2E, ca + cb[c].x));
            o.y = FAST_EXP2(fmaf(p1, L2E, ca + cb[c].y));
            o.z = FAST_EXP2(fmaf(p2, L2E, ca + cb[c].z));
            o.w = FAST_EXP2(fmaf(p3, L2E, ca + cb[c].w));
            *reinterpret_cast<float4*>(op + c * 256) = o;   // 4 back-to-back -> 4KB run
        }
    }
}

extern "C" void kernel_launch(void* const* d_in, const int* in_sizes, int n_in,
                              void* d_out, int out_size, void* d_ws, size_t ws_size,
                              hipStream_t stream) {
    (void)in_sizes; (void)n_in; (void)d_ws; (void)ws_size; (void)out_size;
    const float* x1  = (const float*)d_in[0];
    const float* x2  = (const float*)d_in[1];
    const float* ls  = (const float*)d_in[2];
    const float* osc = (const float*)d_in[3];
    float* out = (float*)d_out;

    const int N1 = 4096, N2 = 4096;
    rbf_kernel<<<dim3(512), dim3(256), 0, stream>>>(x1, x2, ls, osc, out, N1, N2);
}